// Round 4
// baseline (130.290 us; speedup 1.0000x reference)
//
#include <hip/hip_runtime.h>
#include <stdint.h>

#define D 128
#define MCOLS 196      // 14*14
#define XPITCH 232     // xc pitch (bf16); 116 dwords == 20 mod 32 -> 2-way (free)
#define BPITCH 136     // NS buffer pitch; 68 dwords == 4 mod 32 -> 2-way (free)
#define KOUT 8256      // 128*129/2

typedef short v8s __attribute__((ext_vector_type(8)));
typedef float v4f __attribute__((ext_vector_type(4)));

__device__ __forceinline__ uint32_t f2bf(float f) {
    uint32_t u = __builtin_bit_cast(uint32_t, f);
    u += 0x7FFFu + ((u >> 16) & 1u);   // RNE
    return u >> 16;
}
__device__ __forceinline__ float bf2f(uint32_t s) {
    uint32_t u = (s & 0xFFFFu) << 16;
    return __builtin_bit_cast(float, u);
}
__device__ __forceinline__ uint64_t pack4bf(float a, float b, float c, float d) {
    return (uint64_t)f2bf(a) | ((uint64_t)f2bf(b) << 16) |
           ((uint64_t)f2bf(c) << 32) | ((uint64_t)f2bf(d) << 48);
}

// Barrier WITHOUT vmcnt drain: keeps prefetch global_loads in flight across
// LDS-ordering barriers (hipcc's __syncthreads emits vmcnt(0) which would
// serialize the cross-batch pipeline). lgkmcnt(0) orders all LDS ops;
// sched_barrier(0) prevents post-barrier ds_reads hoisting above s_barrier.
__device__ __forceinline__ void barrier_nd() {
    asm volatile("s_waitcnt lgkmcnt(0)" ::: "memory");
    __builtin_amdgcn_s_barrier();
    __builtin_amdgcn_sched_barrier(0);
}

// Persistent blocks: grid=256 (1 block/CU), each block processes 4 batches,
// prefetching batch k+1's input (registers) during batch k's NS chain.
// 16 waves = 4x4 wave grid, each wave owns a 32x32 region (2x2 16x16 MFMA tiles).
// All NS matrices symmetric (polynomials of A) -> one row-major LDS copy serves
// both MFMA operands. M = c*I + R split; linear terms from per-wave f32 register
// copies. cov computed on UNCENTERED bf16; exact f32 rank-1 mean correction.
__global__ __launch_bounds__(1024, 4) void mpncov_kernel(const float* __restrict__ x,
                                                         float* __restrict__ out) {
    __shared__ __align__(16) uint16_t lds[4 * D * BPITCH];   // 139264 B
    __shared__ float meanv[D];
    __shared__ float redbuf[4];

    uint16_t* const B0 = lds;
    uint16_t* const B1 = lds + 1 * D * BPITCH;
    uint16_t* const B2 = lds + 2 * D * BPITCH;
    uint16_t* const B3 = lds + 3 * D * BPITCH;
    // xc (128 x 232 bf16 = 59392 B) overlays B2+B3 (69632 B): those two buffers
    // are dead from MM5-reads-done until MM1/MM2 of the next batch.
    uint16_t (*const xc)[XPITCH] = reinterpret_cast<uint16_t(*)[XPITCH]>(B2);

    const int tid = threadIdx.x;
    const int lane = tid & 63;
    const int w = tid >> 6, wr = w >> 2, wc = w & 3;
    const int lr = lane & 15, lk = lane >> 4;

    // ---- cross-batch prefetch state: 6272 float4 chunks, 49 per row ----
    float4 pf[7];
    uint64_t pk[7];
    auto prefetch = [&](int bbn) {
        const float4* p4 = reinterpret_cast<const float4*>(x + (size_t)bbn * (D * MCOLS));
#pragma unroll
        for (int i = 0; i < 6; ++i) pf[i] = p4[tid + 1024 * i];
        if (tid < 128) pf[6] = p4[tid + 6144];
    };
    auto cvt_pf = [&]() {   // f32 -> packed bf16 (frees half the prefetch regs)
#pragma unroll
        for (int i = 0; i < 6; ++i) pk[i] = pack4bf(pf[i].x, pf[i].y, pf[i].z, pf[i].w);
        if (tid < 128) pk[6] = pack4bf(pf[6].x, pf[6].y, pf[6].z, pf[6].w);
    };
    auto do_pack = [&]() {   // scatter packed bf16 to xc + re-zero K-pad
#pragma unroll
        for (int i = 0; i < 6; ++i) {
            const int c = tid + 1024 * i, row = c / 49, j = c - row * 49;
            *reinterpret_cast<uint64_t*>(&xc[row][4 * j]) = pk[i];
        }
        if (tid < 128) {
            const int c = tid + 6144, row = c / 49, j = c - row * 49;
            *reinterpret_cast<uint64_t*>(&xc[row][4 * j]) = pk[6];
        }
        if (tid < 896) {
            const int row = tid / 7, p = tid - row * 7;
            *reinterpret_cast<uint64_t*>(&xc[row][MCOLS + 4 * p]) = 0ull;
        }
    };

    v4f acc[2][2];
    auto zacc = [&]() {
#pragma unroll
        for (int i = 0; i < 2; ++i)
#pragma unroll
            for (int j = 0; j < 2; ++j) acc[i][j] = v4f{0.f, 0.f, 0.f, 0.f};
    };
    auto matmul = [&](const uint16_t* P, const uint16_t* Q) {
        zacc();
#pragma unroll
        for (int kk = 0; kk < 4; ++kk) {
            const int k0 = kk * 32 + lk * 8;
            v8s af[2], bf[2];
#pragma unroll
            for (int i = 0; i < 2; ++i)
                af[i] = *reinterpret_cast<const v8s*>(&P[(32 * wr + 16 * i + lr) * BPITCH + k0]);
#pragma unroll
            for (int j = 0; j < 2; ++j)
                bf[j] = *reinterpret_cast<const v8s*>(&Q[(32 * wc + 16 * j + lr) * BPITCH + k0]);
#pragma unroll
            for (int i = 0; i < 2; ++i)
#pragma unroll
                for (int j = 0; j < 2; ++j)
                    acc[i][j] = __builtin_amdgcn_mfma_f32_16x16x32_bf16(af[i], bf[j], acc[i][j], 0, 0, 0);
        }
    };
    auto store2 = [&](uint16_t* dst, const v4f (&mm)[2][2]) {   // symmetric: store transposed
#pragma unroll
        for (int i = 0; i < 2; ++i) {
            const int r0 = 32 * wr + 16 * i + 4 * lk;
#pragma unroll
            for (int j = 0; j < 2; ++j) {
                const int c = 32 * wc + 16 * j + lr;
                *reinterpret_cast<uint64_t*>(&dst[c * BPITCH + r0]) =
                    pack4bf(mm[i][j][0], mm[i][j][1], mm[i][j][2], mm[i][j][3]);
            }
        }
    };

    v4f regA[2][2], regY1[2][2], regZY1[2][2], regY2[2][2];

    // ---- prime batch 0 ----
    prefetch(4 * blockIdx.x);
    cvt_pf();
    do_pack();

    for (int it = 0; it < 4; ++it) {
        const int bb = 4 * blockIdx.x + it;
        barrier_nd();                              // b1: xc ready (also fences prev MM6 LDS reads)

        // ---- mean pass: m_r = (1/M) sum of bf16 row r ----
        {
            const int r = tid >> 3, q = tid & 7;
            float s = 0.f;
#pragma unroll
            for (int i = 0; i < 3; ++i) {
                uint4 v = *reinterpret_cast<const uint4*>(&xc[r][8 * (q + 8 * i)]);
                uint32_t a4[4] = {v.x, v.y, v.z, v.w};
#pragma unroll
                for (int k2 = 0; k2 < 4; ++k2) s += bf2f(a4[k2]) + bf2f(a4[k2] >> 16);
            }
            if (q == 0) {
                uint64_t g = *reinterpret_cast<const uint64_t*>(&xc[r][192]);
                s += bf2f((uint32_t)g) + bf2f((uint32_t)(g >> 16)) +
                     bf2f((uint32_t)(g >> 32)) + bf2f((uint32_t)(g >> 48));
            }
            s += __shfl_xor(s, 1); s += __shfl_xor(s, 2); s += __shfl_xor(s, 4);
            if (q == 0) meanv[r] = s * (1.0f / MCOLS);
        }
        barrier_nd();                              // b_m: meanv visible

        // ---- cov: XX^T on uncentered bf16 (K padded to 224) ----
        zacc();
#pragma unroll
        for (int kk = 0; kk < 7; ++kk) {
            const int k0 = kk * 32 + lk * 8;
            v8s af[2], bf[2];
#pragma unroll
            for (int i = 0; i < 2; ++i)
                af[i] = *reinterpret_cast<const v8s*>(&xc[32 * wr + 16 * i + lr][k0]);
#pragma unroll
            for (int j = 0; j < 2; ++j)
                bf[j] = *reinterpret_cast<const v8s*>(&xc[32 * wc + 16 * j + lr][k0]);
#pragma unroll
            for (int i = 0; i < 2; ++i)
#pragma unroll
                for (int j = 0; j < 2; ++j)
                    acc[i][j] = __builtin_amdgcn_mfma_f32_16x16x32_bf16(af[i], bf[j], acc[i][j], 0, 0, 0);
        }
        if (it < 3) prefetch(bb + 1);              // HBM stream hides under NS chain

        // ---- exact f32 centering fix: acc -= M * m_r * m_c ----
        {
            v4f mrow[2]; float mcol[2];
#pragma unroll
            for (int i = 0; i < 2; ++i)
                mrow[i] = *reinterpret_cast<const v4f*>(&meanv[32 * wr + 16 * i + 4 * lk]);
#pragma unroll
            for (int j = 0; j < 2; ++j) mcol[j] = meanv[32 * wc + 16 * j + lr];
#pragma unroll
            for (int i = 0; i < 2; ++i)
#pragma unroll
                for (int j = 0; j < 2; ++j)
#pragma unroll
                    for (int q = 0; q < 4; ++q)
                        acc[i][j][q] -= (float)MCOLS * mrow[i][q] * mcol[j];
        }
        // trace of centered covraw (C/D layout col=lane&15, row=(lane>>4)*4+q)
        float tval = 0.f;
        if (wr == wc && (lr >> 2) == lk) {
            const int qq = lr & 3;
            tval = acc[0][0][qq] + acc[1][1][qq];
        }
#pragma unroll
        for (int off = 32; off; off >>= 1) tval += __shfl_down(tval, off);
        if (wr == wc && lane == 0) redbuf[wr] = tval;
        store2(B0, acc);                           // covM (UNNORMALIZED); true RA = inv*covM
        barrier_nd();                              // b2: covM + redbuf ready; xc dead

        const float tr = (redbuf[0] + redbuf[1]) + (redbuf[2] + redbuf[3]);
        const float inv = 1.0f / tr;
        const float inv2 = inv * inv;
        const float outscale = sqrtf(tr * (1.0f / MCOLS));
#pragma unroll
        for (int i = 0; i < 2; ++i)
#pragma unroll
            for (int j = 0; j < 2; ++j)
#pragma unroll
                for (int q = 0; q < 4; ++q) regA[i][j][q] = inv * acc[i][j][q];

        // MM1: RY1 = -0.5*inv^2*(C@C) + 1.5*RA
        matmul(B0, B0);
#pragma unroll
        for (int i = 0; i < 2; ++i)
#pragma unroll
            for (int j = 0; j < 2; ++j)
#pragma unroll
                for (int q = 0; q < 4; ++q)
                    regY1[i][j][q] = -0.5f * inv2 * acc[i][j][q] + 1.5f * regA[i][j][q];
        store2(B2, regY1);
        if (it < 3) cvt_pf();                      // loads returned by now; frees f32 regs
        barrier_nd();                              // b3

        // MM2: RZY1 = 0.25*inv*(C@RY1) - 0.75*RY1
        matmul(B0, B2);
#pragma unroll
        for (int i = 0; i < 2; ++i)
#pragma unroll
            for (int j = 0; j < 2; ++j)
#pragma unroll
                for (int q = 0; q < 4; ++q)
                    regZY1[i][j][q] = 0.25f * inv * acc[i][j][q] - 0.75f * regY1[i][j][q];
        store2(B3, regZY1);
        barrier_nd();                              // b4

        // MM3: RY2 = RY1@RZY1 + 1.5*RY1
        matmul(B2, B3);
#pragma unroll
        for (int i = 0; i < 2; ++i)
#pragma unroll
            for (int j = 0; j < 2; ++j)
#pragma unroll
                for (int q = 0; q < 4; ++q)
                    regY2[i][j][q] = acc[i][j][q] + 1.5f * regY1[i][j][q];
        store2(B1, regY2);
        barrier_nd();                              // b5

        // MM4: RZ2 = -0.5*inv*(RZY1@C) - 0.75*RA + 1.5*RZY1
        matmul(B3, B0);
#pragma unroll
        for (int i = 0; i < 2; ++i)
#pragma unroll
            for (int j = 0; j < 2; ++j)
#pragma unroll
                for (int q = 0; q < 4; ++q)
                    acc[i][j][q] = -0.5f * inv * acc[i][j][q] - 0.75f * regA[i][j][q] + 1.5f * regZY1[i][j][q];
        store2(B2, acc);                           // Z2 (Y1 slot dead)
        barrier_nd();                              // b6

        // MM5: RT2 = RZ2@RY2 + 2.25*RY2
        matmul(B2, B1);
#pragma unroll
        for (int i = 0; i < 2; ++i)
#pragma unroll
            for (int j = 0; j < 2; ++j)
#pragma unroll
                for (int q = 0; q < 4; ++q)
                    acc[i][j][q] = acc[i][j][q] + 2.25f * regY2[i][j][q];
        store2(B0, acc);                           // T2 (A slot dead)
        barrier_nd();                              // b7

        // MM6: O = 1.5*RY2 - 0.5*(RY2@RT2); upper-tri only
        if (wr <= wc) {
            zacc();
#pragma unroll
            for (int kk = 0; kk < 4; ++kk) {
                const int k0 = kk * 32 + lk * 8;
                v8s af[2], bf[2];
#pragma unroll
                for (int i = 0; i < 2; ++i)
                    af[i] = *reinterpret_cast<const v8s*>(&B1[(32 * wr + 16 * i + lr) * BPITCH + k0]);
#pragma unroll
                for (int j = 0; j < 2; ++j)
                    bf[j] = *reinterpret_cast<const v8s*>(&B0[(32 * wc + 16 * j + lr) * BPITCH + k0]);
#pragma unroll
                for (int i = 0; i < 2; ++i)
#pragma unroll
                    for (int j = 0; j < 2; ++j)
                        if (2 * wr + i <= 2 * wc + j)
                            acc[i][j] = __builtin_amdgcn_mfma_f32_16x16x32_bf16(af[i], bf[j], acc[i][j], 0, 0, 0);
            }
            float* ob = out + (size_t)bb * KOUT;
#pragma unroll
            for (int i = 0; i < 2; ++i) {
                const int r0 = 32 * wr + 16 * i + 4 * lk;
#pragma unroll
                for (int j = 0; j < 2; ++j) {
                    const int rb = 2 * wr + i, cb = 2 * wc + j;
                    if (rb > cb) continue;
                    const int c = 32 * wc + 16 * j + lr;
                    float vv[4];
#pragma unroll
                    for (int q = 0; q < 4; ++q)
                        vv[q] = (1.5f * regY2[i][j][q] - 0.5f * acc[i][j][q]) * outscale;
                    if (rb < cb) {
#pragma unroll
                        for (int q = 0; q < 4; ++q) {
                            const int r = r0 + q;
                            ob[r * D - (r * (r + 1)) / 2 + c] = vv[q];
                        }
                    } else {
#pragma unroll
                        for (int q = 0; q < 4; ++q) {
                            const int r = r0 + q;
                            if (r <= c) ob[r * D - (r * (r + 1)) / 2 + c] = vv[q];
                        }
                    }
                }
            }
        }
        if (it < 3) do_pack();                     // xc(k+1) into B2/B3 (dead), overlaps MM6
    }
}

extern "C" void kernel_launch(void* const* d_in, const int* in_sizes, int n_in,
                              void* d_out, int out_size, void* d_ws, size_t ws_size,
                              hipStream_t stream) {
    const float* x = (const float*)d_in[0];
    float* out = (float*)d_out;
    mpncov_kernel<<<dim3(256), dim3(1024), 0, stream>>>(x, out);
}